// Round 6
// baseline (15087.193 us; speedup 1.0000x reference)
//
#include <hip/hip_runtime.h>

// GRU: T=1024 B=64 D=256 H=512 O=256.
// Round 8: register-direct fragments, repaired. R5's abort traced to (a)
// missing __launch_bounds__(384,2) -> possible >256 VGPR compile -> 6-wave
// block unlaunchable; (b) poll loads and s_waitcnt in SEPARATE asm blocks
// with untied fence (rule-18 hazard): check could read a register before its
// in-flight load landed -> sentinel into MFMA -> NaN -> f2b(NaN)==sentinel ->
// group deadlock. Fixes, all R2-proven patterns:
//  - ONE mega-asm: 16 poll loads + 8 xa loads + s_waitcnt vmcnt(8), outputs
//    tied. In-order vmcnt retirement => polls retired, xa(8) left in flight.
//  - Re-poll: one asm, 16 loads + vmcnt(0), outputs tied.
//  - Validity = all 4 dwords != sentinel (no 16B-atomicity assumption);
//    own-slice bit masked, own fragment taken from h_out LDS.
//  - x-MFMAs at next step top (xa fenced there with tied vmcnt(0)).
//  - Bx in LDS (per-wave private slots) to cut VGPR pressure.
//  - __launch_bounds__(384,2), two __syncthreads (nothing in flight there).
// Gates, wave-1 16B publish, sentinel hs, XCD fast/slow consensus: R2-verbatim.

#define T_ 1024
#define B_ 64
#define D_ 256
#define H_ 512
#define G_ 1536
#define O_ 256

#define SENT32 0x7FC07FC0u   // bf16 NaN pair: unreachable from f2b(finite)

typedef __attribute__((ext_vector_type(8))) short short8;
typedef __attribute__((ext_vector_type(4))) short short4v;
typedef __attribute__((ext_vector_type(4))) float float4v;
typedef __attribute__((ext_vector_type(4))) unsigned int uint4v;

static __device__ __forceinline__ unsigned short f2b(float f) {
  unsigned u = __builtin_bit_cast(unsigned, f);
  u += 0x7fffu + ((u >> 16) & 1u);          // RNE (finite inputs)
  return (unsigned short)(u >> 16);
}

// ---------------------------------------------------------------- prep ------
__global__ __launch_bounds__(256) void prep_kernel(
    const float* __restrict__ x, const float* __restrict__ Wi,
    const float* __restrict__ Wh, const float* __restrict__ Wo,
    unsigned short* __restrict__ xb, unsigned short* __restrict__ WhT,
    unsigned short* __restrict__ WiT, unsigned short* __restrict__ WoT,
    unsigned short* __restrict__ hs, unsigned* __restrict__ xccbuf)
{
  const size_t NX4 = (size_t)T_ * B_ * D_ / 4;   // float4 -> 4 bf16
  const size_t NWH = (size_t)G_ * H_;
  const size_t NWI = (size_t)G_ * D_;
  const size_t NWO = (size_t)O_ * H_;
  const size_t NH8 = (size_t)T_ * B_ * H_ / 8;   // uint4 sentinel chunks
  const size_t NXC = 256;
  const size_t NTOT = NX4 + NWH + NWI + NWO + NH8 + NXC;
  size_t i = (size_t)blockIdx.x * blockDim.x + threadIdx.x;
  const size_t stride = (size_t)gridDim.x * blockDim.x;
  for (; i < NTOT; i += stride) {
    if (i < NX4) {
      float4v f = ((const float4v*)x)[i];
      short4v o;
      o[0] = (short)f2b(f[0]); o[1] = (short)f2b(f[1]);
      o[2] = (short)f2b(f[2]); o[3] = (short)f2b(f[3]);
      ((short4v*)xb)[i] = o;
      continue;
    }
    size_t j = i - NX4;
    if (j < NWH) { size_t g = j >> 9, k = j & 511; WhT[j] = f2b(Wh[k * G_ + g]); continue; }
    j -= NWH;
    if (j < NWI) { size_t g = j >> 8, k = j & 255; WiT[j] = f2b(Wi[k * G_ + g]); continue; }
    j -= NWI;
    if (j < NWO) { size_t o = j >> 9, k = j & 511; WoT[j] = f2b(Wo[k * O_ + o]); continue; }
    j -= NWO;
    if (j < NH8) {
      uint4v sv = {0x7FC07FC0u, 0x7FC07FC0u, 0x7FC07FC0u, 0x7FC07FC0u};
      ((uint4v*)hs)[j] = sv;
      continue;
    }
    j -= NH8;
    xccbuf[j] = 0u;
  }
}

// ---------------------------------------------------------------- scan ------
// 128 WGs x 384 thr launched; active iff (wg&7)<4 -> 64 active WGs.
// group = wg&7 (16 rows), slice = wg>>3 (32 h-cols). Under round-robin XCD
// dispatch all 16 WGs of a group share one XCD (one shared L2).
// wave = s*3 + gk? No: gk = wave%3, s = wave/3; gate-cols = gk*512+slice*32+s*16.

// 16 fragment polls + 8 xa loads + counted wait, ONE asm block (loads and
// waitcnt inseparable; outputs tied => no consumer can precede the wait).
#define POLLXA(F)                                                             \
  asm volatile(                                                               \
    "global_load_dwordx4 %0,  %24, off offset:0 "   F "\n\t"                  \
    "global_load_dwordx4 %1,  %24, off offset:64 "  F "\n\t"                  \
    "global_load_dwordx4 %2,  %24, off offset:128 " F "\n\t"                  \
    "global_load_dwordx4 %3,  %24, off offset:192 " F "\n\t"                  \
    "global_load_dwordx4 %4,  %24, off offset:256 " F "\n\t"                  \
    "global_load_dwordx4 %5,  %24, off offset:320 " F "\n\t"                  \
    "global_load_dwordx4 %6,  %24, off offset:384 " F "\n\t"                  \
    "global_load_dwordx4 %7,  %24, off offset:448 " F "\n\t"                  \
    "global_load_dwordx4 %8,  %24, off offset:512 " F "\n\t"                  \
    "global_load_dwordx4 %9,  %24, off offset:576 " F "\n\t"                  \
    "global_load_dwordx4 %10, %24, off offset:640 " F "\n\t"                  \
    "global_load_dwordx4 %11, %24, off offset:704 " F "\n\t"                  \
    "global_load_dwordx4 %12, %24, off offset:768 " F "\n\t"                  \
    "global_load_dwordx4 %13, %24, off offset:832 " F "\n\t"                  \
    "global_load_dwordx4 %14, %24, off offset:896 " F "\n\t"                  \
    "global_load_dwordx4 %15, %24, off offset:960 " F "\n\t"                  \
    "global_load_dwordx4 %16, %25, off offset:0\n\t"                          \
    "global_load_dwordx4 %17, %25, off offset:64\n\t"                         \
    "global_load_dwordx4 %18, %25, off offset:128\n\t"                        \
    "global_load_dwordx4 %19, %25, off offset:192\n\t"                        \
    "global_load_dwordx4 %20, %25, off offset:256\n\t"                        \
    "global_load_dwordx4 %21, %25, off offset:320\n\t"                        \
    "global_load_dwordx4 %22, %25, off offset:384\n\t"                        \
    "global_load_dwordx4 %23, %25, off offset:448\n\t"                        \
    "s_waitcnt vmcnt(8)"                                                      \
    : "=v"(f[0]), "=v"(f[1]), "=v"(f[2]), "=v"(f[3]),                         \
      "=v"(f[4]), "=v"(f[5]), "=v"(f[6]), "=v"(f[7]),                         \
      "=v"(f[8]), "=v"(f[9]), "=v"(f[10]), "=v"(f[11]),                       \
      "=v"(f[12]), "=v"(f[13]), "=v"(f[14]), "=v"(f[15]),                     \
      "=v"(xa[0]), "=v"(xa[1]), "=v"(xa[2]), "=v"(xa[3]),                     \
      "=v"(xa[4]), "=v"(xa[5]), "=v"(xa[6]), "=v"(xa[7])                      \
    : "v"(srow), "v"(xp) : "memory");                                         \
  __builtin_amdgcn_sched_barrier(0);

#define REPOLL(F)                                                             \
  asm volatile(                                                               \
    "global_load_dwordx4 %0,  %16, off offset:0 "   F "\n\t"                  \
    "global_load_dwordx4 %1,  %16, off offset:64 "  F "\n\t"                  \
    "global_load_dwordx4 %2,  %16, off offset:128 " F "\n\t"                  \
    "global_load_dwordx4 %3,  %16, off offset:192 " F "\n\t"                  \
    "global_load_dwordx4 %4,  %16, off offset:256 " F "\n\t"                  \
    "global_load_dwordx4 %5,  %16, off offset:320 " F "\n\t"                  \
    "global_load_dwordx4 %6,  %16, off offset:384 " F "\n\t"                  \
    "global_load_dwordx4 %7,  %16, off offset:448 " F "\n\t"                  \
    "global_load_dwordx4 %8,  %16, off offset:512 " F "\n\t"                  \
    "global_load_dwordx4 %9,  %16, off offset:576 " F "\n\t"                  \
    "global_load_dwordx4 %10, %16, off offset:640 " F "\n\t"                  \
    "global_load_dwordx4 %11, %16, off offset:704 " F "\n\t"                  \
    "global_load_dwordx4 %12, %16, off offset:768 " F "\n\t"                  \
    "global_load_dwordx4 %13, %16, off offset:832 " F "\n\t"                  \
    "global_load_dwordx4 %14, %16, off offset:896 " F "\n\t"                  \
    "global_load_dwordx4 %15, %16, off offset:960 " F "\n\t"                  \
    "s_waitcnt vmcnt(0)"                                                      \
    : "=v"(f[0]), "=v"(f[1]), "=v"(f[2]), "=v"(f[3]),                         \
      "=v"(f[4]), "=v"(f[5]), "=v"(f[6]), "=v"(f[7]),                         \
      "=v"(f[8]), "=v"(f[9]), "=v"(f[10]), "=v"(f[11]),                       \
      "=v"(f[12]), "=v"(f[13]), "=v"(f[14]), "=v"(f[15])                      \
    : "v"(srow) : "memory");                                                  \
  __builtin_amdgcn_sched_barrier(0);

#define CHECKF(BAD)                                                           \
  BAD = 0u;                                                                   \
  _Pragma("unroll")                                                           \
  for (int k2 = 0; k2 < 16; ++k2) {                                           \
    uint4v u_ = __builtin_bit_cast(uint4v, f[k2]);                            \
    unsigned h_ = (unsigned)((u_[0] == SENT32) | (u_[1] == SENT32) |          \
                             (u_[2] == SENT32) | (u_[3] == SENT32));          \
    BAD |= h_ << k2;                                                          \
  }                                                                           \
  BAD &= ~(1u << slice);

__global__ __launch_bounds__(384, 2) void scan_kernel(
    const unsigned short* __restrict__ xb,
    const unsigned short* __restrict__ WhT,
    const unsigned short* __restrict__ WiT,
    unsigned short* __restrict__ hs,
    const float* __restrict__ bi,
    const float* __restrict__ bhn,
    const float* __restrict__ h0,
    unsigned* __restrict__ xccbuf)
{
  const int wg = blockIdx.x;
  const int group = wg & 7;
  if (group >= 4) return;                     // 64 active WGs on XCDs 0..3
  const int slice = wg >> 3;                  // 0..15
  const int tid = threadIdx.x;
  const int wave = tid >> 6;
  const int lane = tid & 63;
  const int m = lane & 15;
  const int quad = lane >> 4;
  const int gk = wave % 3;
  const int s = wave / 3;
  const int row0 = group * 16;
  const int jbase = slice * 32 + s * 16;
  const int gcol = gk * 512 + jbase + m;

  struct HX { float h, x; };
  __shared__ HX lds_hx[6][256];               // pre-activation exchange (12KB)
  __shared__ unsigned short h_out[16 * 32];   // this WG's h slice (1KB)
  __shared__ unsigned short BxL[48 * 512];    // per-wave Wi fragments (48KB)
  __shared__ int fast_lds;

  // Bh fragments persistent in VGPRs; Bx staged to per-wave LDS slots.
  short8 Bh[16];
  {
    const unsigned short* p = WhT + (size_t)gcol * H_ + quad * 8;
#pragma unroll
    for (int k = 0; k < 16; ++k) Bh[k] = *(const short8*)(p + k * 32);
    const unsigned short* q = WiT + (size_t)gcol * D_ + quad * 8;
#pragma unroll
    for (int k = 0; k < 8; ++k)
      *(short8*)&BxL[(wave * 8 + k) * 512 + lane * 8] = *(const short8*)(q + k * 32);
  }

  const int jcol = jbase + m;
  const float bi_r = bi[jcol];
  const float bi_z = bi[512 + jcol];
  const float bi_n = bi[1024 + jcol];
  const float bhn_c = bhn[jcol];
  float hold[4];
#pragma unroll
  for (int i = 0; i < 4; ++i)
    hold[i] = h0[(size_t)(row0 + quad * 4 + i) * H_ + jcol];

  // A-fragments of current h: f[k] = h[row0+m][k*32+quad*8 .. +8].
  // t=0: built from h0 (fp32 -> bf16) in registers.
  short8 f[16];
#pragma unroll
  for (int k = 0; k < 16; ++k) {
    const float* hp = h0 + (size_t)(row0 + m) * H_ + k * 32 + quad * 8;
    float4v a = *(const float4v*)hp;
    float4v b = *(const float4v*)(hp + 4);
    short8 o;
    o[0] = (short)f2b(a[0]); o[1] = (short)f2b(a[1]);
    o[2] = (short)f2b(a[2]); o[3] = (short)f2b(a[3]);
    o[4] = (short)f2b(b[0]); o[5] = (short)f2b(b[1]);
    o[6] = (short)f2b(b[2]); o[7] = (short)f2b(b[3]);
    f[k] = o;
  }

  // ---- one-time XCD-homogeneity consensus (per group; identical verdicts) --
  {
    unsigned xcc;
    asm("s_getreg_b32 %0, hwreg(HW_REG_XCC_ID)" : "=s"(xcc));
    if (tid == 0) {
      unsigned tok = xcc + 1u;
      unsigned* slot = xccbuf + wg;
      asm volatile("global_store_dword %0, %1, off sc0 sc1"
                   :: "v"(slot), "v"(tok) : "memory");
    }
    if (wave == 0) {
      unsigned val = 0xffffffffu;
      if (lane < 16) {
        const unsigned* p = xccbuf + group + 8 * lane;   // the 16 group members
        do {
          asm volatile("global_load_dword %0, %1, off sc0 sc1\n\t"
                       "s_waitcnt vmcnt(0)" : "=&v"(val) : "v"(p));
        } while (val == 0u);
      }
      unsigned ref = __shfl(val, 0, 64);
      bool ok = (lane < 16) ? (val == ref) : true;
      if (lane == 0) fast_lds = (__ballot(ok) == ~0ull) ? 1 : 0;
    }
  }
  asm volatile("s_waitcnt vmcnt(0) lgkmcnt(0)" ::: "memory");
  __syncthreads();
  const bool fast = (fast_lds != 0);

  // xa for t=0 (fenced at phase 1.5 of the first iteration)
  short8 xa[8];
  {
    const unsigned short* xp0 = xb + ((size_t)0 * B_ + row0 + m) * D_ + quad * 8;
    asm volatile(
      "global_load_dwordx4 %0, %8, off offset:0\n\t"
      "global_load_dwordx4 %1, %8, off offset:64\n\t"
      "global_load_dwordx4 %2, %8, off offset:128\n\t"
      "global_load_dwordx4 %3, %8, off offset:192\n\t"
      "global_load_dwordx4 %4, %8, off offset:256\n\t"
      "global_load_dwordx4 %5, %8, off offset:320\n\t"
      "global_load_dwordx4 %6, %8, off offset:384\n\t"
      "global_load_dwordx4 %7, %8, off offset:448"
      : "=v"(xa[0]), "=v"(xa[1]), "=v"(xa[2]), "=v"(xa[3]),
        "=v"(xa[4]), "=v"(xa[5]), "=v"(xa[6]), "=v"(xa[7])
      : "v"(xp0) : "memory");
  }

  for (int t = 0; t < T_; ++t) {
    // ---- phase 1: h-MFMAs straight from the A-fragment registers ----------
    float4v acch0 = {0.f, 0.f, 0.f, 0.f}, acch1 = {0.f, 0.f, 0.f, 0.f};
#pragma unroll
    for (int k = 0; k < 16; k += 2) {
      acch0 = __builtin_amdgcn_mfma_f32_16x16x32_bf16(f[k],     Bh[k],     acch0, 0, 0, 0);
      acch1 = __builtin_amdgcn_mfma_f32_16x16x32_bf16(f[k + 1], Bh[k + 1], acch1, 0, 0, 0);
    }
    // ---- phase 1.5: x-MFMAs for this t (xa fenced with tied vmcnt) --------
    asm volatile("s_waitcnt vmcnt(0)"
                 : "+v"(xa[0]), "+v"(xa[1]), "+v"(xa[2]), "+v"(xa[3]),
                   "+v"(xa[4]), "+v"(xa[5]), "+v"(xa[6]), "+v"(xa[7])
                 :: "memory");
    __builtin_amdgcn_sched_barrier(0);
    float4v accx;
    {
      float4v ax0 = {0.f, 0.f, 0.f, 0.f}, ax1 = {0.f, 0.f, 0.f, 0.f};
#pragma unroll
      for (int k = 0; k < 8; k += 2) {
        ax0 = __builtin_amdgcn_mfma_f32_16x16x32_bf16(xa[k],     *(const short8*)&BxL[(wave * 8 + k)     * 512 + lane * 8], ax0, 0, 0, 0);
        ax1 = __builtin_amdgcn_mfma_f32_16x16x32_bf16(xa[k + 1], *(const short8*)&BxL[(wave * 8 + k + 1) * 512 + lane * 8], ax1, 0, 0, 0);
      }
#pragma unroll
      for (int i = 0; i < 4; ++i) accx[i] = ax0[i] + ax1[i];
    }
    // ---- phase 2: exchange pre-activations --------------------------------
#pragma unroll
    for (int i = 0; i < 4; ++i) {
      const int idx = (quad * 4 + i) * 16 + m;
      HX v; v.h = acch0[i] + acch1[i]; v.x = accx[i];
      lds_hx[wave][idx] = v;
    }
    __syncthreads();                          // B1
    // ---- phase 3: gates on gk==0 waves -> h_out ---------------------------
    if (gk == 0) {
      const int wb = s * 3;
#pragma unroll
      for (int i = 0; i < 4; ++i) {
        const int r = quad * 4 + i;
        const int idx = r * 16 + m;
        const HX vr = lds_hx[wb + 0][idx];
        const HX vz = lds_hx[wb + 1][idx];
        const HX vn = lds_hx[wb + 2][idx];
        const float pr = vr.h + vr.x + bi_r;
        const float pz = vz.h + vz.x + bi_z;
        const float rg = 1.f / (1.f + __expf(-pr));
        const float zg = 1.f / (1.f + __expf(-pz));
        const float an = vn.x + bi_n + rg * (vn.h + bhn_c);
        const float e2 = __expf(2.f * an);          // branch-free tanh
        const float ng = 1.f - 2.f / (e2 + 1.f);
        const float hn = (1.f - zg) * ng + zg * hold[i];
        hold[i] = hn;
        h_out[r * 32 + s * 16 + m] = f2b(hn);
      }
    }
    __syncthreads();                          // B2
    // ---- phase 4: wave1 publishes this WG's 1KB slice (16B stores) --------
    if (wave == 1) {
      const int r = lane >> 2, c8 = (lane & 3) * 8;
      short8 hv = *(const short8*)&h_out[r * 32 + c8];
      unsigned short* dst = hs + ((size_t)t * B_ + row0 + r) * H_ + slice * 32 + c8;
      if (fast)
        asm volatile("global_store_dwordx4 %0, %1, off sc0"
                     :: "v"(dst), "v"(hv) : "memory");
      else
        asm volatile("global_store_dwordx4 %0, %1, off sc0 sc1"
                     :: "v"(dst), "v"(hv) : "memory");
    }
    if (t == T_ - 1) break;                   // final h published; done

    // ---- phase 5: poll all 16 fragments into A-registers + issue xa -------
    const unsigned short* srow = hs + ((size_t)t * B_ + row0 + m) * H_ + quad * 8;
    const unsigned short* xp = xb + ((size_t)(t + 1) * B_ + row0 + m) * D_ + quad * 8;
    unsigned bad;
    if (fast) { POLLXA("sc0") } else { POLLXA("sc0 sc1") }
    CHECKF(bad);
    while (__any((int)(bad != 0u))) {
      if (fast) { REPOLL("sc0") } else { REPOLL("sc0 sc1") }
      CHECKF(bad);
    }
    // own slice from LDS (authoritative; overwrites the unchecked global copy)
    f[slice] = *(const short8*)&h_out[m * 32 + quad * 8];
  }
}

// ---------------------------------------------------------------- ogemm -----
__global__ __launch_bounds__(256) void ogemm_kernel(
    const unsigned short* __restrict__ hs, const unsigned short* __restrict__ WoT,
    const float* __restrict__ bo, float* __restrict__ out)
{
  const int wv = threadIdx.x >> 6, lane = threadIdx.x & 63;
  const int m = lane & 15, quad = lane >> 4;
  const int rowbase = blockIdx.x * 64 + wv * 16;
  const unsigned short* ap = hs + (size_t)(rowbase + m) * H_ + quad * 8;
  float4v acc[16];
#pragma unroll
  for (int n = 0; n < 16; ++n) { float4v z = {0.f,0.f,0.f,0.f}; acc[n] = z; }
#pragma unroll
  for (int k = 0; k < 16; ++k) {
    short8 a = *(const short8*)(ap + k * 32);
#pragma unroll
    for (int n = 0; n < 16; ++n) {
      short8 b = *(const short8*)(WoT + (size_t)(n * 16 + m) * H_ + k * 32 + quad * 8);
      acc[n] = __builtin_amdgcn_mfma_f32_16x16x32_bf16(a, b, acc[n], 0, 0, 0);
    }
  }
#pragma unroll
  for (int n = 0; n < 16; ++n) {
    const int col = n * 16 + m;
    const float bias = bo[col];
#pragma unroll
    for (int i = 0; i < 4; ++i) {
      const int r = rowbase + quad * 4 + i;
      out[(size_t)r * O_ + col] = acc[n][i] + bias;
    }
  }
}

// ---------------------------------------------------------------- launch ----
extern "C" void kernel_launch(void* const* d_in, const int* in_sizes, int n_in,
                              void* d_out, int out_size, void* d_ws, size_t ws_size,
                              hipStream_t stream)
{
  const float* x   = (const float*)d_in[0];
  const float* Wi  = (const float*)d_in[1];
  const float* bi  = (const float*)d_in[2];
  const float* Wh  = (const float*)d_in[3];
  const float* bhn = (const float*)d_in[4];
  const float* Wo  = (const float*)d_in[5];
  const float* bo  = (const float*)d_in[6];
  const float* h0  = (const float*)d_in[7];
  float* out = (float*)d_out;

  char* ws = (char*)d_ws;
  unsigned short* xb  = (unsigned short*)ws;  ws += (size_t)T_ * B_ * D_ * 2;  // 33.5 MB
  unsigned short* WhT = (unsigned short*)ws;  ws += (size_t)G_ * H_ * 2;       // 1.5 MB
  unsigned short* WiT = (unsigned short*)ws;  ws += (size_t)G_ * D_ * 2;       // 0.75 MB
  unsigned short* WoT = (unsigned short*)ws;  ws += (size_t)O_ * H_ * 2;       // 0.25 MB
  unsigned short* hs  = (unsigned short*)ws;  ws += (size_t)T_ * B_ * H_ * 2;  // 67 MB
  unsigned* xccbuf    = (unsigned*)ws;                                          // 1 KB

  prep_kernel<<<4096, 256, 0, stream>>>(x, Wi, Wh, Wo, xb, WhT, WiT, WoT, hs, xccbuf);
  scan_kernel<<<128, 384, 0, stream>>>(xb, WhT, WiT, hs, bi, bhn, h0, xccbuf);
  ogemm_kernel<<<1024, 256, 0, stream>>>(hs, WoT, bo, out);
}